// Round 1
// baseline (156.448 us; speedup 1.0000x reference)
//
#include <hip/hip_runtime.h>
#include <math.h>

// ---------------------------------------------------------------------------
// Problem constants: H=8, D=256, DH=32, SH=64, B=4, L_LEFT=128, L_RIGHT=256.
// BH = 32.  Output: concat(out_l [4,128,256], out_r [4,256,256]) = 393216 f32.
// ---------------------------------------------------------------------------

#define LOG2E 1.4426950408889634f
#define SCALE2 (2.0f * LOG2E)   // prescale for qf/kf so exp2(qf'+kf') = e^{2x}

// workspace offsets in floats (total 1,966,080 floats = 7.86 MB)
#define OFF_QFL 0          // [32][128][64]
#define OFF_KFL 262144     // [32][16][256][4]  (h-interleaved by 4)
#define OFF_QFR 786432     // [32][256][64]
#define OFF_KFR 1310720    // [32][16][128][4]
#define OFF_HOL 1572864    // [4][128][256] merged-head attention out (left)
#define OFF_HOR 1703936    // [4][256][256] merged-head attention out (right)

static __device__ __forceinline__ float fast_exp2(float x) {
#if __has_builtin(__builtin_amdgcn_exp2f)
    return __builtin_amdgcn_exp2f(x);
#else
    return exp2f(x);
#endif
}

static __device__ __forceinline__ float fast_rcp(float x) {
#if __has_builtin(__builtin_amdgcn_rcpf)
    return __builtin_amdgcn_rcpf(x);
#else
    return 1.0f / x;
#endif
}

// r(x) = 1 / (1 + 2^x).  tanh contribution: wv*tanh = wv - 2*wv*r.
static __device__ __forceinline__ float sigm2(float x) {
    return fast_rcp(1.0f + fast_exp2(x));
}

// ---------------------------------------------------------------------------
// K1: feature projections.  4 jobs: qf_l, kf_l, qf_r, kf_r.
//   qf'[bh][l][h]            = SCALE2 * sum_j X[b][l][hd*32+j] * W[j][h]
//   kf4'[bh][h>>2][l][h&3]   = same, h-interleaved for float4 reads in K2.
// grid: 64 + 128 + 128 + 64 = 384 blocks of 256 threads.
// Thread: lane h = t&63 owns feature h (W column in regs), lsub = t>>6 owns
// 16 l-rows; X row reads are lane-uniform float4 (single-line broadcasts).
// ---------------------------------------------------------------------------
__global__ __launch_bounds__(256) void k1_proj(
    const float* __restrict__ ql, const float* __restrict__ kr,
    const float* __restrict__ qr, const float* __restrict__ kl,
    const float* __restrict__ wql, const float* __restrict__ wkl,
    const float* __restrict__ wqr, const float* __restrict__ wkr,
    float* __restrict__ ws)
{
    int blk = blockIdx.x;
    const float* X; const float* W; float* out; int L; int ktype;
    if (blk < 64)       { X = ql; W = wql; out = ws + OFF_QFL; L = 128; ktype = 0; }
    else if (blk < 192) { X = kr; W = wkl; out = ws + OFF_KFL; L = 256; ktype = 1; blk -= 64; }
    else if (blk < 320) { X = qr; W = wqr; out = ws + OFF_QFR; L = 256; ktype = 0; blk -= 192; }
    else                { X = kl; W = wkr; out = ws + OFF_KFR; L = 128; ktype = 1; blk -= 320; }

    const int tiles = L >> 6;                 // 64-row tiles
    const int bh = blk / tiles;
    const int l0 = (blk - bh * tiles) << 6;
    const int b = bh >> 3, hd = bh & 7;
    const int t = threadIdx.x;
    const int h = t & 63, lsub = t >> 6;

    float wcol[32];
#pragma unroll
    for (int j = 0; j < 32; ++j) wcol[j] = W[j * 64 + h];   // coalesced per j

    const float* xb = X + ((b * L + l0 + lsub * 16) * 256) + hd * 32;

#pragma unroll 4
    for (int i = 0; i < 16; ++i) {
        const float4* xp = (const float4*)(xb + i * 256);
        float acc = 0.f;
#pragma unroll
        for (int j4 = 0; j4 < 8; ++j4) {
            float4 a = xp[j4];
            acc += a.x * wcol[4 * j4 + 0];
            acc += a.y * wcol[4 * j4 + 1];
            acc += a.z * wcol[4 * j4 + 2];
            acc += a.w * wcol[4 * j4 + 3];
        }
        acc *= SCALE2;
        const int l = l0 + lsub * 16 + i;
        if (!ktype) out[(bh * L + l) * 64 + h] = acc;
        else        out[bh * (L * 64) + (h >> 2) * (L * 4) + l * 4 + (h & 3)] = acc;
    }
}

// ---------------------------------------------------------------------------
// K2: fused additive attention (scores -> masked softmax -> PV) per
// (bh, 8-row q-tile).  One launch covers both sides:
//   blocks [0,512):   left  (LK=256, LQ=128)
//   blocks [512,1536): right (LK=128, LQ=256)
// Thread t owns score column k = t % LK (group g = t / LK owns row half).
// Scores accumulate as  s~ = sum_h c_h / (1 + exp2(qf'+kf'))  with
// c_h = -2*log2(e)*wv_h, which equals log2(e)*(true_score - const); softmax
// via exp2 on s~ is then exactly the e-softmax of the true scores.
// ---------------------------------------------------------------------------
template<int LK, int LQ>
__device__ __forceinline__ void attn_side(
    int bh, int q0,
    const float* qf, const float* kf4,
    const float* __restrict__ wv, const float* __restrict__ v,
    const int* __restrict__ vlen, float* ho,
    float* s_lds, float* pv_lds, float* c_lds)
{
    constexpr int TQ  = 8;          // q-rows per block
    constexpr int G   = 256 / LK;   // thread groups over rows
    constexpr int RPT = TQ / G;     // rows per thread
    const int t = threadIdx.x;

    if (t < 64) c_lds[t] = wv[t] * (-2.0f * LOG2E);
    __syncthreads();

    const int k = t & (LK - 1);
    const int g = (LK == 256) ? 0 : (t >> 7);
    const int b = bh >> 3, hd = bh & 7;
    const int valid = vlen[b];

    // ---- Phase A: scores -------------------------------------------------
    float acc[RPT];
#pragma unroll
    for (int r = 0; r < RPT; ++r) acc[r] = 0.f;

    const float* kfp = kf4 + bh * (64 * LK) + k * 4;
    const float* qfp = qf + (bh * LQ + q0 + g * RPT) * 64;

#pragma unroll 4
    for (int hc = 0; hc < 16; ++hc) {
        const float4 kv = *(const float4*)(kfp + hc * (LK * 4));
        const float4 cv = *(const float4*)(c_lds + hc * 4);
#pragma unroll
        for (int r = 0; r < RPT; ++r) {
            const float4 qv = *(const float4*)(qfp + r * 64 + hc * 4);
            acc[r] += cv.x * sigm2(qv.x + kv.x);
            acc[r] += cv.y * sigm2(qv.y + kv.y);
            acc[r] += cv.z * sigm2(qv.z + kv.z);
            acc[r] += cv.w * sigm2(qv.w + kv.w);
        }
    }
#pragma unroll
    for (int r = 0; r < RPT; ++r) {
        const int row = g * RPT + r;
        s_lds[row * LK + k] = (k < valid) ? acc[r] : -1.0e6f;
    }
    __syncthreads();

    // ---- Phase B: masked softmax (per-wave, 2 rows per wave) -------------
    {
        const int wid = t >> 6, lane = t & 63;
        constexpr int CPL = LK / 64;
#pragma unroll
        for (int rr = 0; rr < 2; ++rr) {
            const int row = wid * 2 + rr;
            float sv[CPL];
            float m = -3.0e38f;
#pragma unroll
            for (int j = 0; j < CPL; ++j) {
                sv[j] = s_lds[row * LK + lane + 64 * j];
                m = fmaxf(m, sv[j]);
            }
#pragma unroll
            for (int off = 1; off < 64; off <<= 1) m = fmaxf(m, __shfl_xor(m, off));
            float lsum = 0.f;
#pragma unroll
            for (int j = 0; j < CPL; ++j) { sv[j] = fast_exp2(sv[j] - m); lsum += sv[j]; }
#pragma unroll
            for (int off = 1; off < 64; off <<= 1) lsum += __shfl_xor(lsum, off);
            const float inv = fast_rcp(lsum);
#pragma unroll
            for (int j = 0; j < CPL; ++j) s_lds[row * LK + lane + 64 * j] = sv[j] * inv;
        }
    }
    __syncthreads();

    // ---- Phase C: PV.  thread = (d = t&31, kc = t>>5); v-slice in regs ----
    {
        const int d = t & 31, kc = t >> 5;
        constexpr int CS = LK / 8;
        float vv[CS];
        const float* vp = v + (b * LK + kc * CS) * 256 + hd * 32 + d;
#pragma unroll
        for (int i = 0; i < CS; ++i) vv[i] = vp[i * 256];
#pragma unroll
        for (int row = 0; row < TQ; ++row) {
            const float4* pp = (const float4*)(s_lds + row * LK + kc * CS);
            float a = 0.f;
#pragma unroll
            for (int i4 = 0; i4 < CS / 4; ++i4) {
                float4 p = pp[i4];
                a += p.x * vv[4 * i4 + 0];
                a += p.y * vv[4 * i4 + 1];
                a += p.z * vv[4 * i4 + 2];
                a += p.w * vv[4 * i4 + 3];
            }
            pv_lds[(kc * TQ + row) * 32 + d] = a;
        }
    }
    __syncthreads();

    // ---- Phase D: reduce 8 kc-partials, write merged-head layout ---------
    {
        const int dd = t & 31, row = t >> 5;   // 8 rows x 32 d = 256 threads
        float o = 0.f;
#pragma unroll
        for (int kc2 = 0; kc2 < 8; ++kc2) o += pv_lds[(kc2 * TQ + row) * 32 + dd];
        ho[(b * LQ + q0 + row) * 256 + hd * 32 + dd] = o;
    }
}

__global__ __launch_bounds__(256) void k2_attn(
    float* ws,
    const float* __restrict__ wvl, const float* __restrict__ wvr,
    const float* __restrict__ vr, const float* __restrict__ vl,
    const int* __restrict__ vlr, const int* __restrict__ vll)
{
    __shared__ __align__(16) float s_lds[2048];
    __shared__ __align__(16) float pv_lds[2048];
    __shared__ __align__(16) float c_lds[64];
    int blk = blockIdx.x;
    if (blk < 512) {
        const int bh = blk >> 4, q0 = (blk & 15) << 3;
        attn_side<256, 128>(bh, q0, ws + OFF_QFL, ws + OFF_KFL, wvl, vr, vlr,
                            ws + OFF_HOL, s_lds, pv_lds, c_lds);
    } else {
        blk -= 512;
        const int bh = blk >> 5, q0 = (blk & 31) << 3;
        attn_side<128, 256>(bh, q0, ws + OFF_QFR, ws + OFF_KFR, wvr, vl, vll,
                            ws + OFF_HOR, s_lds, pv_lds, c_lds);
    }
}

// ---------------------------------------------------------------------------
// K3: output projections.  rows 0..511 = left (@ Wo_l), 512..1535 = right.
// 8 rows per block, thread = output column; A-tile staged in LDS (broadcast
// float4 reads), Wo rows read coalesced from L2.
// ---------------------------------------------------------------------------
__global__ __launch_bounds__(256) void k3_proj(
    const float* ws,
    const float* __restrict__ wol, const float* __restrict__ wor,
    float* __restrict__ out)
{
    __shared__ __align__(16) float a_lds[2048];
    const int row0 = blockIdx.x * 8;
    const float* A; const float* W; float* op; int lr0;
    if (row0 < 512) { A = ws + OFF_HOL; W = wol; op = out;          lr0 = row0; }
    else            { A = ws + OFF_HOR; W = wor; op = out + 131072; lr0 = row0 - 512; }

    const int t = threadIdx.x;
#pragma unroll
    for (int i = 0; i < 8; ++i) a_lds[i * 256 + t] = A[lr0 * 256 + i * 256 + t];
    __syncthreads();

    float acc[8];
#pragma unroll
    for (int r = 0; r < 8; ++r) acc[r] = 0.f;

#pragma unroll 4
    for (int k4 = 0; k4 < 64; ++k4) {
        const float w0 = W[(k4 * 4 + 0) * 256 + t];
        const float w1 = W[(k4 * 4 + 1) * 256 + t];
        const float w2 = W[(k4 * 4 + 2) * 256 + t];
        const float w3 = W[(k4 * 4 + 3) * 256 + t];
#pragma unroll
        for (int r = 0; r < 8; ++r) {
            const float4 a = *(const float4*)(a_lds + r * 256 + k4 * 4);
            acc[r] += a.x * w0 + a.y * w1 + a.z * w2 + a.w * w3;
        }
    }
#pragma unroll
    for (int r = 0; r < 8; ++r) op[(lr0 + r) * 256 + t] = acc[r];
}

// ---------------------------------------------------------------------------
extern "C" void kernel_launch(void* const* d_in, const int* in_sizes, int n_in,
                              void* d_out, int out_size, void* d_ws, size_t ws_size,
                              hipStream_t stream)
{
    const float* ql  = (const float*)d_in[0];
    const float* kr  = (const float*)d_in[1];
    const float* vr  = (const float*)d_in[2];
    const float* qr  = (const float*)d_in[3];
    const float* kl  = (const float*)d_in[4];
    const float* vl  = (const float*)d_in[5];
    const float* wql = (const float*)d_in[6];
    const float* wkl = (const float*)d_in[7];
    const float* wvl = (const float*)d_in[8];
    const float* wol = (const float*)d_in[9];
    const float* wqr = (const float*)d_in[10];
    const float* wkr = (const float*)d_in[11];
    const float* wvr = (const float*)d_in[12];
    const float* wor = (const float*)d_in[13];
    const int*   vlr = (const int*)d_in[14];
    const int*   vll = (const int*)d_in[15];
    float* ws  = (float*)d_ws;
    float* out = (float*)d_out;

    hipLaunchKernelGGL(k1_proj, dim3(384), dim3(256), 0, stream,
                       ql, kr, qr, kl, wql, wkl, wqr, wkr, ws);
    hipLaunchKernelGGL(k2_attn, dim3(1536), dim3(256), 0, stream,
                       ws, wvl, wvr, vr, vl, vlr, vll);
    hipLaunchKernelGGL(k3_proj, dim3(192), dim3(256), 0, stream,
                       ws, wol, wor, out);
}

// Round 2
// 134.287 us; speedup vs baseline: 1.1650x; 1.1650x over previous
//
#include <hip/hip_runtime.h>
#include <math.h>

// ---------------------------------------------------------------------------
// Problem constants: H=8, D=256, DH=32, SH=64, B=4, L_LEFT=128, L_RIGHT=256.
// BH = 32.  Output: concat(out_l [4,128,256], out_r [4,256,256]) = 393216 f32.
// ---------------------------------------------------------------------------

#define LOG2E 1.4426950408889634f
#define SCALE2 (2.0f * LOG2E)   // prescale for qf/kf so exp2(qf'+kf') = e^{2x}

// workspace offsets in floats (total 1,966,080 floats = 7.86 MB)
#define OFF_QFL 0          // [32][128][64]
#define OFF_KFL 262144     // [32][16][256][4]  (h-interleaved by 4)
#define OFF_QFR 786432     // [32][256][64]
#define OFF_KFR 1310720    // [32][16][128][4]
#define OFF_HOL 1572864    // [4][128][256] merged-head attention out (left)
#define OFF_HOR 1703936    // [4][256][256] merged-head attention out (right)

static __device__ __forceinline__ float fast_exp2(float x) {
#if __has_builtin(__builtin_amdgcn_exp2f)
    return __builtin_amdgcn_exp2f(x);
#else
    return exp2f(x);
#endif
}

static __device__ __forceinline__ float fast_rcp(float x) {
#if __has_builtin(__builtin_amdgcn_rcpf)
    return __builtin_amdgcn_rcpf(x);
#else
    return 1.0f / x;
#endif
}

// r(x) = 1 / (1 + 2^x).  tanh contribution: wv*tanh = wv - 2*wv*r.
static __device__ __forceinline__ float sigm2(float x) {
    return fast_rcp(1.0f + fast_exp2(x));
}

// ---------------------------------------------------------------------------
// K1: feature projections.  4 jobs: qf_l, kf_l, qf_r, kf_r.
//   qf'[bh][l][h]            = SCALE2 * sum_j X[b][l][hd*32+j] * W[j][h]
//   kf4'[bh][h>>2][l][h&3]   = same, h-interleaved for float4 reads in K2.
// grid: 1536 blocks of 256 (16 l-rows per block; thread = (h, 4-row slice)).
// ---------------------------------------------------------------------------
__global__ __launch_bounds__(256) void k1_proj(
    const float* __restrict__ ql, const float* __restrict__ kr,
    const float* __restrict__ qr, const float* __restrict__ kl,
    const float* __restrict__ wql, const float* __restrict__ wkl,
    const float* __restrict__ wqr, const float* __restrict__ wkr,
    float* __restrict__ ws)
{
    int blk = blockIdx.x;
    const float* X; const float* W; float* out; int L; int ktype;
    if (blk < 256)       { X = ql; W = wql; out = ws + OFF_QFL; L = 128; ktype = 0; }
    else if (blk < 768)  { X = kr; W = wkl; out = ws + OFF_KFL; L = 256; ktype = 1; blk -= 256; }
    else if (blk < 1280) { X = qr; W = wqr; out = ws + OFF_QFR; L = 256; ktype = 0; blk -= 768; }
    else                 { X = kl; W = wkr; out = ws + OFF_KFR; L = 128; ktype = 1; blk -= 1280; }

    const int tiles = L >> 4;                 // 16-row tiles
    const int bh = blk / tiles;
    const int l0 = (blk - bh * tiles) << 4;
    const int b = bh >> 3, hd = bh & 7;
    const int t = threadIdx.x;
    const int h = t & 63, lsub = t >> 6;      // 4 rows per thread

    float wcol[32];
#pragma unroll
    for (int j = 0; j < 32; ++j) wcol[j] = W[j * 64 + h];   // coalesced per j

    const float* xb = X + ((b * L + l0 + lsub * 4) * 256) + hd * 32;

#pragma unroll
    for (int i = 0; i < 4; ++i) {
        const float4* xp = (const float4*)(xb + i * 256);
        float acc = 0.f;
#pragma unroll
        for (int j4 = 0; j4 < 8; ++j4) {
            float4 a = xp[j4];
            acc += a.x * wcol[4 * j4 + 0];
            acc += a.y * wcol[4 * j4 + 1];
            acc += a.z * wcol[4 * j4 + 2];
            acc += a.w * wcol[4 * j4 + 3];
        }
        acc *= SCALE2;
        const int l = l0 + lsub * 4 + i;
        if (!ktype) out[(bh * L + l) * 64 + h] = acc;
        else        out[bh * (L * 64) + (h >> 2) * (L * 4) + l * 4 + (h & 3)] = acc;
    }
}

// ---------------------------------------------------------------------------
// K2: fused additive attention (scores -> masked softmax -> PV).
// Uniform blocks: left TQ=4 (1024 blocks), right TQ=8 (1024 blocks); every
// block/thread does exactly 256 sigm2 evals.  Wave-granular mask skip: a wave
// whose whole k-range is >= valid skips Phase A compute (~30% avg savings).
// Scores accumulate as  s~ = sum_h c_h / (1 + exp2(qf'+kf'))  with
// c_h = -2*log2(e)*wv_h  == log2(e)*(true_score - const); exp2-softmax on s~
// is exactly the e-softmax of the true scores.
// ---------------------------------------------------------------------------
template<int LK, int LQ, int TQ>
__device__ __forceinline__ void attn_side(
    int bh, int q0,
    const float* qf, const float* kf4,
    const float* __restrict__ wv, const float* __restrict__ v,
    const int* __restrict__ vlen, float* ho,
    float* s_lds, float* pv_lds, float* c_lds)
{
    constexpr int G   = 256 / LK;   // thread groups over rows
    constexpr int RPT = TQ / G;     // rows per thread
    const int t = threadIdx.x;

    if (t < 64) c_lds[t] = wv[t] * (-2.0f * LOG2E);
    __syncthreads();

    const int k = t & (LK - 1);
    const int g = (LK == 256) ? 0 : (t >> 7);
    const int b = bh >> 3, hd = bh & 7;
    const int valid = vlen[b];

    // ---- Phase A: scores -------------------------------------------------
    float acc[RPT];
#pragma unroll
    for (int r = 0; r < RPT; ++r) acc[r] = 0.f;

    if ((k & ~63) < valid) {        // wave-uniform skip of fully-masked waves
        const float* kfp = kf4 + bh * (64 * LK) + k * 4;
        const float* qfp = qf + (bh * LQ + q0 + g * RPT) * 64;
#pragma unroll 4
        for (int hc = 0; hc < 16; ++hc) {
            const float4 kv = *(const float4*)(kfp + hc * (LK * 4));
            const float4 cv = *(const float4*)(c_lds + hc * 4);
#pragma unroll
            for (int r = 0; r < RPT; ++r) {
                const float4 qv = *(const float4*)(qfp + r * 64 + hc * 4);
                acc[r] += cv.x * sigm2(qv.x + kv.x);
                acc[r] += cv.y * sigm2(qv.y + kv.y);
                acc[r] += cv.z * sigm2(qv.z + kv.z);
                acc[r] += cv.w * sigm2(qv.w + kv.w);
            }
        }
    }
#pragma unroll
    for (int r = 0; r < RPT; ++r) {
        const int row = g * RPT + r;
        s_lds[row * LK + k] = (k < valid) ? acc[r] : -1.0e6f;
    }
    __syncthreads();

    // ---- Phase B: masked softmax (TQ/4 rows per wave) --------------------
    {
        const int wid = t >> 6, lane = t & 63;
        constexpr int RPW = TQ / 4;
        constexpr int CPL = LK / 64;
#pragma unroll
        for (int rr = 0; rr < RPW; ++rr) {
            const int row = wid * RPW + rr;
            float sv[CPL];
            float m = -3.0e38f;
#pragma unroll
            for (int j = 0; j < CPL; ++j) {
                sv[j] = s_lds[row * LK + lane + 64 * j];
                m = fmaxf(m, sv[j]);
            }
#pragma unroll
            for (int off = 1; off < 64; off <<= 1) m = fmaxf(m, __shfl_xor(m, off));
            float lsum = 0.f;
#pragma unroll
            for (int j = 0; j < CPL; ++j) { sv[j] = fast_exp2(sv[j] - m); lsum += sv[j]; }
#pragma unroll
            for (int off = 1; off < 64; off <<= 1) lsum += __shfl_xor(lsum, off);
            const float inv = fast_rcp(lsum);
#pragma unroll
            for (int j = 0; j < CPL; ++j) s_lds[row * LK + lane + 64 * j] = sv[j] * inv;
        }
    }
    __syncthreads();

    // ---- Phase C: PV.  thread = (d = t&31, kc = t>>5); v-slice in regs ----
    {
        const int d = t & 31, kc = t >> 5;
        constexpr int CS = LK / 8;
        if (kc * CS < valid) {
            float vv[CS];
            const float* vp = v + (b * LK + kc * CS) * 256 + hd * 32 + d;
#pragma unroll
            for (int i = 0; i < CS; ++i) vv[i] = vp[i * 256];
#pragma unroll
            for (int row = 0; row < TQ; ++row) {
                const float4* pp = (const float4*)(s_lds + row * LK + kc * CS);
                float a = 0.f;
#pragma unroll
                for (int i4 = 0; i4 < CS / 4; ++i4) {
                    float4 p = pp[i4];
                    a += p.x * vv[4 * i4 + 0];
                    a += p.y * vv[4 * i4 + 1];
                    a += p.z * vv[4 * i4 + 2];
                    a += p.w * vv[4 * i4 + 3];
                }
                pv_lds[(kc * TQ + row) * 32 + d] = a;
            }
        } else {
#pragma unroll
            for (int row = 0; row < TQ; ++row) pv_lds[(kc * TQ + row) * 32 + d] = 0.f;
        }
    }
    __syncthreads();

    // ---- Phase D: reduce 8 kc-partials, write merged-head layout ---------
    if (t < TQ * 32) {
        const int dd = t & 31, row = t >> 5;
        float o = 0.f;
#pragma unroll
        for (int kc2 = 0; kc2 < 8; ++kc2) o += pv_lds[(kc2 * TQ + row) * 32 + dd];
        ho[(b * LQ + q0 + row) * 256 + hd * 32 + dd] = o;
    }
}

__global__ __launch_bounds__(256) void k2_attn(
    float* ws,
    const float* __restrict__ wvl, const float* __restrict__ wvr,
    const float* __restrict__ vr, const float* __restrict__ vl,
    const int* __restrict__ vlr, const int* __restrict__ vll)
{
    __shared__ __align__(16) float s_lds[1024];
    __shared__ __align__(16) float pv_lds[2048];
    __shared__ __align__(16) float c_lds[64];
    int blk = blockIdx.x;
    if (blk < 1024) {                 // left: LK=256, LQ=128, TQ=4
        const int bh = blk >> 5, q0 = (blk & 31) << 2;
        attn_side<256, 128, 4>(bh, q0, ws + OFF_QFL, ws + OFF_KFL, wvl, vr, vlr,
                               ws + OFF_HOL, s_lds, pv_lds, c_lds);
    } else {                          // right: LK=128, LQ=256, TQ=8
        blk -= 1024;
        const int bh = blk >> 5, q0 = (blk & 31) << 3;
        attn_side<128, 256, 8>(bh, q0, ws + OFF_QFR, ws + OFF_KFR, wvr, vl, vll,
                               ws + OFF_HOR, s_lds, pv_lds, c_lds);
    }
}

// ---------------------------------------------------------------------------
// K3: output projections.  4 rows per block -> 384 blocks.
// blocks [0,128): left (@ Wo_l), [128,384): right (@ Wo_r).
// ---------------------------------------------------------------------------
__global__ __launch_bounds__(256) void k3_proj(
    const float* ws,
    const float* __restrict__ wol, const float* __restrict__ wor,
    float* __restrict__ out)
{
    __shared__ __align__(16) float a_lds[1024];
    const int row0 = blockIdx.x * 4;
    const float* A; const float* W; float* op; int lr0;
    if (row0 < 512) { A = ws + OFF_HOL; W = wol; op = out;          lr0 = row0; }
    else            { A = ws + OFF_HOR; W = wor; op = out + 131072; lr0 = row0 - 512; }

    const int t = threadIdx.x;
#pragma unroll
    for (int i = 0; i < 4; ++i) a_lds[i * 256 + t] = A[(lr0 + i) * 256 + t];
    __syncthreads();

    float acc[4];
#pragma unroll
    for (int r = 0; r < 4; ++r) acc[r] = 0.f;

#pragma unroll 4
    for (int k4 = 0; k4 < 64; ++k4) {
        const float w0 = W[(k4 * 4 + 0) * 256 + t];
        const float w1 = W[(k4 * 4 + 1) * 256 + t];
        const float w2 = W[(k4 * 4 + 2) * 256 + t];
        const float w3 = W[(k4 * 4 + 3) * 256 + t];
#pragma unroll
        for (int r = 0; r < 4; ++r) {
            const float4 a = *(const float4*)(a_lds + r * 256 + k4 * 4);
            acc[r] += a.x * w0 + a.y * w1 + a.z * w2 + a.w * w3;
        }
    }
#pragma unroll
    for (int r = 0; r < 4; ++r) op[(lr0 + r) * 256 + t] = acc[r];
}

// ---------------------------------------------------------------------------
extern "C" void kernel_launch(void* const* d_in, const int* in_sizes, int n_in,
                              void* d_out, int out_size, void* d_ws, size_t ws_size,
                              hipStream_t stream)
{
    const float* ql  = (const float*)d_in[0];
    const float* kr  = (const float*)d_in[1];
    const float* vr  = (const float*)d_in[2];
    const float* qr  = (const float*)d_in[3];
    const float* kl  = (const float*)d_in[4];
    const float* vl  = (const float*)d_in[5];
    const float* wql = (const float*)d_in[6];
    const float* wkl = (const float*)d_in[7];
    const float* wvl = (const float*)d_in[8];
    const float* wol = (const float*)d_in[9];
    const float* wqr = (const float*)d_in[10];
    const float* wkr = (const float*)d_in[11];
    const float* wvr = (const float*)d_in[12];
    const float* wor = (const float*)d_in[13];
    const int*   vlr = (const int*)d_in[14];
    const int*   vll = (const int*)d_in[15];
    float* ws  = (float*)d_ws;
    float* out = (float*)d_out;

    hipLaunchKernelGGL(k1_proj, dim3(1536), dim3(256), 0, stream,
                       ql, kr, qr, kl, wql, wkl, wqr, wkr, ws);
    hipLaunchKernelGGL(k2_attn, dim3(2048), dim3(256), 0, stream,
                       ws, wvl, wvr, vr, vl, vlr, vll);
    hipLaunchKernelGGL(k3_proj, dim3(384), dim3(256), 0, stream,
                       ws, wol, wor, out);
}